// Round 8
// baseline (86.679 us; speedup 1.0000x reference)
//
#include <hip/hip_runtime.h>

// ConjunctionLayer: out[b,j] = -1 / (-1 + sum_i log(1 - (1-x[b,i]) * W[j,i]))
// B=4096, INPUT_DIM=512, N=128, fp32.
//
// R8: DE-PACK the hot loop. Evidence: R3b/R5/R6 all ~22 us regardless of
// occupancy (2 vs 4 waves), x-load width, or log count; R7 (half the gather)
// regressed via 1 block/CU. The invariant across all four is the packed-f32
// mix. On gfx950 the fp32 pipe peak (157.3 TF) is the UNPACKED rate: a
// v_pk_fma_f32 occupies the pipe 4 cyc vs 2 for v_fma_f32 (no throughput
// gain), and pk ops force even:odd VGPR pairing -> v_mov shuffles all over
// the loop. This round uses all-scalar fmaf/mul:
//   z = fmaf(x, w[i], u[i]) with w[64], u[64]=1-w resident per lane
//   (2 ops/element, the algorithmic floor; no per-element sub),
//   scalar 63-mul product tree per 64-group -> one v_log_f32
//   (product >= 0.5^64 ~ 5e-20, normal fp32).
// Config reverted to R3b/R6 shape: NB=16, 512 blocks x 8 waves, 2 blocks/CU.
// ~192 VGPRs -> 2 waves/SIMD (R5 proved 4 waves buys nothing).

typedef float v4f __attribute__((ext_vector_type(4)));

constexpr int IDIM  = 512;
constexpr int NOUT  = 128;
constexpr int BTOT  = 4096;
constexpr int KC    = 64;            // i per wave
constexpr int NB    = 16;            // b per block
constexpr int GB    = BTOT / NB;     // 256 b-groups
constexpr float LN2 = 0.69314718055994530942f;

// 16-i chunk -> scalar partial product. 16 v_fma_f32 + 15 v_mul_f32.
__device__ __forceinline__ float chunk16(float4 a0, float4 a1, float4 a2, float4 a3,
                                         const float* __restrict__ w,
                                         const float* __restrict__ u) {
    float z0  = fmaf(a0.x, w[0],  u[0]);
    float z1  = fmaf(a0.y, w[1],  u[1]);
    float z2  = fmaf(a0.z, w[2],  u[2]);
    float z3  = fmaf(a0.w, w[3],  u[3]);
    float z4  = fmaf(a1.x, w[4],  u[4]);
    float z5  = fmaf(a1.y, w[5],  u[5]);
    float z6  = fmaf(a1.z, w[6],  u[6]);
    float z7  = fmaf(a1.w, w[7],  u[7]);
    float z8  = fmaf(a2.x, w[8],  u[8]);
    float z9  = fmaf(a2.y, w[9],  u[9]);
    float z10 = fmaf(a2.z, w[10], u[10]);
    float z11 = fmaf(a2.w, w[11], u[11]);
    float z12 = fmaf(a3.x, w[12], u[12]);
    float z13 = fmaf(a3.y, w[13], u[13]);
    float z14 = fmaf(a3.z, w[14], u[14]);
    float z15 = fmaf(a3.w, w[15], u[15]);
    float p0 = (z0 * z1)   * (z2 * z3);
    float p1 = (z4 * z5)   * (z6 * z7);
    float p2 = (z8 * z9)   * (z10 * z11);
    float p3 = (z12 * z13) * (z14 * z15);
    return (p0 * p1) * (p2 * p3);
}

__global__ __launch_bounds__(512, 2)
void conj_kernel(const float* __restrict__ x,
                 const float* __restrict__ W,
                 float* __restrict__ out)
{
    __shared__ float s_p[NB * 8 * 64];   // [bi][wave][lane] partials, 32 KB

    const int tid  = threadIdx.x;
    const int lane = tid & 63;
    const int wv   = __builtin_amdgcn_readfirstlane(tid >> 6);   // 0..7, SGPR
    const int h    = blockIdx.x >> 8;        // j-half; pairs 256 apart -> same XCD
    const int bg   = blockIdx.x & (GB - 1);
    const int b0   = bg * NB;
    const int j    = h * 64 + lane;
    const int k0   = wv * KC;

    // Loop-invariant per-lane W fragment: w = W[j, k0:k0+64], u = 1 - w.
    // 128 VGPRs. One-time row-strided gather (R7 showed it's not dominant).
    float w[KC], u[KC];
    {
        const v4f* wp = (const v4f*)(W + (size_t)j * IDIM + k0);
        #pragma unroll
        for (int qd = 0; qd < 16; ++qd) {
            v4f t = wp[qd];
            w[4 * qd + 0] = t.x;  u[4 * qd + 0] = 1.0f - t.x;
            w[4 * qd + 1] = t.y;  u[4 * qd + 1] = 1.0f - t.y;
            w[4 * qd + 2] = t.z;  u[4 * qd + 2] = 1.0f - t.z;
            w[4 * qd + 3] = t.w;  u[4 * qd + 3] = 1.0f - t.w;
        }
    }

    // x stream: wave-uniform addresses, float4 granularity.
    // idx(bi, c, q) = bi*128 + c*4 + q   (row stride 512 floats = 128 float4)
    const float4* xq = (const float4*)(x + (size_t)b0 * IDIM + k0);

    // Prime the pipeline with chunk (bi=0, c=0).
    float4 xa0 = xq[0], xa1 = xq[1], xa2 = xq[2], xa3 = xq[3];

    for (int bi = 0; bi < NB; ++bi) {
        float pc[4];
        #pragma unroll
        for (int c = 0; c < 4; ++c) {
            // Prefetch next 16-float chunk (clamped reload on the last one).
            int nbi = (c == 3) ? bi + 1 : bi;
            int nc  = (c == 3) ? 0 : c + 1;
            if (nbi == NB) { nbi = NB - 1; nc = 3; }
            const int ni = nbi * 128 + nc * 4;
            float4 xb0 = xq[ni + 0], xb1 = xq[ni + 1];
            float4 xb2 = xq[ni + 2], xb3 = xq[ni + 3];

            pc[c] = chunk16(xa0, xa1, xa2, xa3, &w[c * 16], &u[c * 16]);

            xa0 = xb0; xa1 = xb1; xa2 = xb2; xa3 = xb3;
        }
        const float m = (pc[0] * pc[1]) * (pc[2] * pc[3]);
        // product of all 64 z's in (0.5^64, 1] -> one log2
        s_p[bi * 512 + wv * 64 + lane] = __builtin_amdgcn_logf(m);
    }
    __syncthreads();

    // Reduce the 8 K-chunks, finalize, coalesced store. 2 outputs/thread.
    #pragma unroll
    for (int r = 0; r < (NB * 64) / 512; ++r) {
        const int idx = tid + r * 512;
        const int bi  = idx >> 6;
        const int l   = idx & 63;
        float sum = 0.0f;
        #pragma unroll
        for (int wq = 0; wq < 8; ++wq)
            sum += s_p[bi * 512 + wq * 64 + l];   // lanes consecutive: no conflict
        out[(size_t)(b0 + bi) * NOUT + h * 64 + l] = 1.0f / (1.0f - LN2 * sum);
    }
}

extern "C" void kernel_launch(void* const* d_in, const int* in_sizes, int n_in,
                              void* d_out, int out_size, void* d_ws, size_t ws_size,
                              hipStream_t stream) {
    const float* x = (const float*)d_in[0];   // (4096, 512) fp32
    const float* W = (const float*)d_in[1];   // (128, 512) fp32
    float* out = (float*)d_out;               // (4096, 128) fp32

    dim3 grid(2 * GB);                        // 512 blocks (j-half major)
    dim3 block(512);                          // 8 waves
    hipLaunchKernelGGL(conj_kernel, grid, block, 0, stream, x, W, out);
}